// Round 5
// baseline (63.589 us; speedup 1.0000x reference)
//
#include <hip/hip_runtime.h>
#include <hip/hip_bf16.h>

// Problem constants (B=1, S=5, Q=512, T=64, D=2048)
#define S_DIM 5
#define Q_DIM 512
#define T_DIM 64
#define D_DIM 2048
#define EPS_CS 1e-8f

typedef float f32x4 __attribute__((ext_vector_type(4)));

// Workspace layout (floats):
//   sp       : [S_DIM][D_DIM] @ 0      (10240)
//   snpart   : [S_DIM][8]     @ 10240  (40)   partial sum-of-squares per (s,chunk)
//   loss_acc : float          @ 10280
//   counter  : uint           @ 10281
#define WS_SP     0
#define WS_SNPART 10240
#define WS_LOSS   10280
#define WS_CNT    10281

__device__ __forceinline__ float wave_reduce_sum(float v) {
    #pragma unroll
    for (int off = 32; off > 0; off >>= 1)
        v += __shfl_down(v, off, 64);
    return v;
}

__device__ __forceinline__ float dot4(f32x4 a, f32x4 b) {
    return a.x * b.x + a.y * b.y + a.z * b.z + a.w * b.w;
}

// Kernel 1: pool supp over T -> sp[s][d] (+ per-(s,chunk) sum-of-squares).
// Also zero-inits the loss accumulator and completion counter for K2.
// 40 blocks x 512 threads; block = (s, c).
__global__ __launch_bounds__(512) void supp_pool_kernel(
    const float* __restrict__ supp, float* __restrict__ sp,
    float* __restrict__ snpart, float* __restrict__ loss_acc,
    unsigned int* __restrict__ counter)
{
    if (blockIdx.x == 0 && threadIdx.x == 0) {
        *loss_acc = 0.0f;
        *counter  = 0u;
    }

    const int s    = blockIdx.x >> 3;
    const int c    = blockIdx.x & 7;
    const int tg   = threadIdx.x >> 6;   // 8 t-groups
    const int lane = threadIdx.x & 63;
    const int slot = c * 64 + lane;      // f32x4 slot in [0, 512)

    const f32x4* base = (const f32x4*)(supp + (size_t)s * T_DIM * D_DIM);

    f32x4 acc = {0.f, 0.f, 0.f, 0.f};
    #pragma unroll
    for (int i = 0; i < 8; ++i) {
        const int t = tg * 8 + i;
        acc += base[t * (D_DIM / 4) + slot];
    }

    __shared__ f32x4 lds[8][64];
    lds[tg][lane] = acc;
    __syncthreads();
    if (tg == 0) {
        f32x4 tot = lds[0][lane];
        #pragma unroll
        for (int w = 1; w < 8; ++w) tot += lds[w][lane];
        tot *= (1.0f / (float)T_DIM);
        ((f32x4*)(sp + (size_t)s * D_DIM))[slot] = tot;

        float sq = wave_reduce_sum(dot4(tot, tot));
        if (lane == 0) snpart[s * 8 + c] = sq;
    }
}

// Kernel 2: one block per q. Pool query row over T (268 MB stream), dot vs
// 5 sp rows + self-dot, dist, (1-dist) output row, nll; the last block to
// finish writes out[0] = mean(nll). 512 blocks x 512 threads.
__global__ __launch_bounds__(512) void query_fused_kernel(
    const float* __restrict__ query, const float* __restrict__ sp,
    const float* __restrict__ snpart, const int* __restrict__ ys,
    float* __restrict__ out, float* __restrict__ loss_acc,
    unsigned int* __restrict__ counter)
{
    const int q   = blockIdx.x;
    const int tid = threadIdx.x;
    const f32x4* base = (const f32x4*)(query + (size_t)q * T_DIM * D_DIM);

    f32x4 acc = {0.f, 0.f, 0.f, 0.f};
    #pragma unroll 8
    for (int t = 0; t < T_DIM; ++t)
        acc += base[t * (D_DIM / 4) + tid];
    acc *= (1.0f / (float)T_DIM);

    // vals: [0..4] qp.sp_s, [5] qp.qp
    float vals[6];
    vals[5] = dot4(acc, acc);
    #pragma unroll
    for (int s = 0; s < S_DIM; ++s) {
        f32x4 sv = ((const f32x4*)(sp + (size_t)s * D_DIM))[tid];
        vals[s] = dot4(acc, sv);
    }

    __shared__ float lds[8][6];
    const int wave = tid >> 6, lane = tid & 63;
    #pragma unroll
    for (int k = 0; k < 6; ++k) {
        float r = wave_reduce_sum(vals[k]);
        if (lane == 0) lds[wave][k] = r;
    }
    __syncthreads();

    if (tid == 0) {
        float tot[6];
        #pragma unroll
        for (int k = 0; k < 6; ++k) {
            float t = 0.f;
            #pragma unroll
            for (int w = 0; w < 8; ++w) t += lds[w][k];
            tot[k] = t;
        }
        const float qn = sqrtf(tot[5]);

        float dist[S_DIM];
        #pragma unroll
        for (int s = 0; s < S_DIM; ++s) {
            float sn2 = 0.f;
            #pragma unroll
            for (int c = 0; c < 8; ++c) sn2 += snpart[s * 8 + c];
            const float sn = sqrtf(sn2);
            const float d  = tot[s] / fmaxf(qn * sn, EPS_CS);
            dist[s] = d;
            out[1 + (size_t)q * S_DIM + s] = 1.0f - d;
        }

        float m = dist[0];
        #pragma unroll
        for (int s = 1; s < S_DIM; ++s) m = fmaxf(m, dist[s]);
        float sum = 0.f;
        #pragma unroll
        for (int s = 0; s < S_DIM; ++s) sum += expf(dist[s] - m);
        const float lse = m + logf(sum);

        int y = ys[q];
        if (y < 0) y = 0;
        if (y >= S_DIM) y = S_DIM - 1;
        const float nll = lse - dist[y];

        // Device-scope loss accumulation; last block finalizes out[0].
        atomicAdd(loss_acc, nll);
        unsigned int old = __hip_atomic_fetch_add(counter, 1u,
                              __ATOMIC_ACQ_REL, __HIP_MEMORY_SCOPE_AGENT);
        if (old == Q_DIM - 1) {
            float tot_loss = __hip_atomic_load(loss_acc,
                                __ATOMIC_ACQUIRE, __HIP_MEMORY_SCOPE_AGENT);
            out[0] = tot_loss * (1.0f / (float)Q_DIM);
        }
    }
}

extern "C" void kernel_launch(void* const* d_in, const int* in_sizes, int n_in,
                              void* d_out, int out_size, void* d_ws, size_t ws_size,
                              hipStream_t stream) {
    const float* supp  = (const float*)d_in[0];
    const float* query = (const float*)d_in[1];
    const int*   ys    = (const int*)d_in[2];
    float* out = (float*)d_out;

    float* ws           = (float*)d_ws;
    float* sp           = ws + WS_SP;
    float* snpart       = ws + WS_SNPART;
    float* loss_acc     = ws + WS_LOSS;
    unsigned int* cnt   = (unsigned int*)(ws + WS_CNT);

    supp_pool_kernel<<<S_DIM * 8, 512, 0, stream>>>(supp, sp, snpart, loss_acc, cnt);
    query_fused_kernel<<<Q_DIM, 512, 0, stream>>>(query, sp, snpart, ys, out, loss_acc, cnt);
}

// Round 6
// 54.210 us; speedup vs baseline: 1.1730x; 1.1730x over previous
//
#include <hip/hip_runtime.h>
#include <hip/hip_bf16.h>

// Problem constants (B=1, S=5, Q=512, T=64, D=2048)
#define S_DIM 5
#define Q_DIM 512
#define T_DIM 64
#define D_DIM 2048
#define EPS_CS 1e-8f

typedef float f32x4 __attribute__((ext_vector_type(4)));

// Workspace layout (floats):
//   sp       : [S_DIM][D_DIM] @ 0      (10240)
//   snpart   : [S_DIM][8]     @ 10240  (40)   partial sum-of-squares per (s,chunk)
//   loss_acc : float          @ 10280
//   counter  : uint           @ 10281
#define WS_SP     0
#define WS_SNPART 10240
#define WS_LOSS   10280
#define WS_CNT    10281

__device__ __forceinline__ float wave_reduce_sum(float v) {
    #pragma unroll
    for (int off = 32; off > 0; off >>= 1)
        v += __shfl_down(v, off, 64);
    return v;
}

__device__ __forceinline__ float dot4(f32x4 a, f32x4 b) {
    return a.x * b.x + a.y * b.y + a.z * b.z + a.w * b.w;
}

// Kernel 1: pool supp over T -> sp[s][d] (+ per-(s,chunk) sum-of-squares).
// Also re-zeroes the loss accumulator and completion counter for K2
// (kernel-end implicit agent release makes these visible to K2's atomics).
// 40 blocks x 512 threads; block = (s, c).
__global__ __launch_bounds__(512) void supp_pool_kernel(
    const float* __restrict__ supp, float* __restrict__ sp,
    float* __restrict__ snpart, float* __restrict__ loss_acc,
    unsigned int* __restrict__ counter)
{
    if (blockIdx.x == 0 && threadIdx.x == 0) {
        *loss_acc = 0.0f;
        *counter  = 0u;
    }

    const int s    = blockIdx.x >> 3;
    const int c    = blockIdx.x & 7;
    const int tg   = threadIdx.x >> 6;   // 8 t-groups
    const int lane = threadIdx.x & 63;
    const int slot = c * 64 + lane;      // f32x4 slot in [0, 512)

    const f32x4* base = (const f32x4*)(supp + (size_t)s * T_DIM * D_DIM);

    f32x4 acc = {0.f, 0.f, 0.f, 0.f};
    #pragma unroll
    for (int i = 0; i < 8; ++i) {
        const int t = tg * 8 + i;
        acc += base[t * (D_DIM / 4) + slot];
    }

    __shared__ f32x4 lds[8][64];
    lds[tg][lane] = acc;
    __syncthreads();
    if (tg == 0) {
        f32x4 tot = lds[0][lane];
        #pragma unroll
        for (int w = 1; w < 8; ++w) tot += lds[w][lane];
        tot *= (1.0f / (float)T_DIM);
        ((f32x4*)(sp + (size_t)s * D_DIM))[slot] = tot;

        float sq = wave_reduce_sum(dot4(tot, tot));
        if (lane == 0) snpart[s * 8 + c] = sq;
    }
}

// Kernel 2: one block per q. Pool query row over T (268 MB stream), dot vs
// 5 sp rows + self-dot, dist, (1-dist) output row, nll. Loss mean is
// accumulated with RELAXED device-scope atomics (no fences -> no L2
// writeback storm); the 512th block to finish reads the total via a
// relaxed RMW and writes out[0]. 512 blocks x 512 threads.
__global__ __launch_bounds__(512) void query_fused_kernel(
    const float* __restrict__ query, const float* __restrict__ sp,
    const float* __restrict__ snpart, const int* __restrict__ ys,
    float* __restrict__ out, float* __restrict__ loss_acc,
    unsigned int* __restrict__ counter)
{
    const int q   = blockIdx.x;
    const int tid = threadIdx.x;
    const f32x4* base = (const f32x4*)(query + (size_t)q * T_DIM * D_DIM);

    f32x4 acc = {0.f, 0.f, 0.f, 0.f};
    #pragma unroll 8
    for (int t = 0; t < T_DIM; ++t)
        acc += base[t * (D_DIM / 4) + tid];
    acc *= (1.0f / (float)T_DIM);

    // vals: [0..4] qp.sp_s, [5] qp.qp
    float vals[6];
    vals[5] = dot4(acc, acc);
    #pragma unroll
    for (int s = 0; s < S_DIM; ++s) {
        f32x4 sv = ((const f32x4*)(sp + (size_t)s * D_DIM))[tid];
        vals[s] = dot4(acc, sv);
    }

    __shared__ float lds[8][6];
    const int wave = tid >> 6, lane = tid & 63;
    #pragma unroll
    for (int k = 0; k < 6; ++k) {
        float r = wave_reduce_sum(vals[k]);
        if (lane == 0) lds[wave][k] = r;
    }
    __syncthreads();

    if (tid == 0) {
        float tot[6];
        #pragma unroll
        for (int k = 0; k < 6; ++k) {
            float t = 0.f;
            #pragma unroll
            for (int w = 0; w < 8; ++w) t += lds[w][k];
            tot[k] = t;
        }
        const float qn = sqrtf(tot[5]);

        float dist[S_DIM];
        #pragma unroll
        for (int s = 0; s < S_DIM; ++s) {
            float sn2 = 0.f;
            #pragma unroll
            for (int c = 0; c < 8; ++c) sn2 += snpart[s * 8 + c];
            const float sn = sqrtf(sn2);
            const float d  = tot[s] / fmaxf(qn * sn, EPS_CS);
            dist[s] = d;
            out[1 + (size_t)q * S_DIM + s] = 1.0f - d;
        }

        float m = dist[0];
        #pragma unroll
        for (int s = 1; s < S_DIM; ++s) m = fmaxf(m, dist[s]);
        float sum = 0.f;
        #pragma unroll
        for (int s = 0; s < S_DIM; ++s) sum += expf(dist[s] - m);
        const float lse = m + logf(sum);

        int y = ys[q];
        if (y < 0) y = 0;
        if (y >= S_DIM) y = S_DIM - 1;
        const float nll = lse - dist[y];

        // Relaxed device-scope accumulation (executes at coherence point,
        // no cache flush). Consume the returned value to force vmcnt-wait:
        // guarantees this block's loss add completed BEFORE its counter
        // increment issues.
        float oldv = atomicAdd(loss_acc, nll);
        __asm__ __volatile__("" :: "v"(oldv) : "memory");

        unsigned int old = atomicAdd(counter, 1u);
        if (old == Q_DIM - 1) {
            // All 512 counter increments observed => all 512 loss adds
            // completed at the coherence point. Read total via relaxed RMW.
            float tot_loss = atomicAdd(loss_acc, 0.0f);
            out[0] = tot_loss * (1.0f / (float)Q_DIM);
        }
    }
}

extern "C" void kernel_launch(void* const* d_in, const int* in_sizes, int n_in,
                              void* d_out, int out_size, void* d_ws, size_t ws_size,
                              hipStream_t stream) {
    const float* supp  = (const float*)d_in[0];
    const float* query = (const float*)d_in[1];
    const int*   ys    = (const int*)d_in[2];
    float* out = (float*)d_out;

    float* ws           = (float*)d_ws;
    float* sp           = ws + WS_SP;
    float* snpart       = ws + WS_SNPART;
    float* loss_acc     = ws + WS_LOSS;
    unsigned int* cnt   = (unsigned int*)(ws + WS_CNT);

    supp_pool_kernel<<<S_DIM * 8, 512, 0, stream>>>(supp, sp, snpart, loss_acc, cnt);
    query_fused_kernel<<<Q_DIM, 512, 0, stream>>>(query, sp, snpart, ys, out, loss_acc, cnt);
}